// Round 1
// baseline (744.345 us; speedup 1.0000x reference)
//
#include <hip/hip_runtime.h>

#define B_ 32
#define P_ 1024
#define V_ 100
#define E_ 512
#define H_ 512
#define C_ 512
#define EPS_ 1e-5f

typedef float f32x4 __attribute__((ext_vector_type(4)));
typedef short bf16x8 __attribute__((ext_vector_type(8)));

#define GLB(p) ((const __attribute__((address_space(1))) unsigned int*)(p))
#define LDSP(p) ((__attribute__((address_space(3))) unsigned int*)(p))

__device__ __forceinline__ unsigned short f2bf(float f) {
  unsigned int u = __float_as_uint(f);
  u += 0x7fffu + ((u >> 16) & 1u);
  return (unsigned short)(u >> 16);
}
__device__ __forceinline__ float bf2f(unsigned short s) {
  return __uint_as_float(((unsigned int)s) << 16);
}

// K1: G[k][v][h] = scale1[h] * sum_e w1[h,e,k] * emb[v,e]
// grid = V_ blocks, 512 threads (one per h)
__global__ void g_kernel(const float* __restrict__ emb, const float* __restrict__ w1,
                         const float* __restrict__ g1, const float* __restrict__ vr1,
                         float* __restrict__ G) {
  __shared__ float se[E_];
  int v = blockIdx.x;
  int h = threadIdx.x;
  se[h] = emb[(size_t)v * E_ + h];
  __syncthreads();
  float a0 = 0.f, a1 = 0.f, a2 = 0.f;
  const float* wrow = w1 + (size_t)h * E_ * 3;
#pragma unroll 4
  for (int e = 0; e < E_; ++e) {
    float x = se[e];
    a0 = fmaf(wrow[e * 3 + 0], x, a0);
    a1 = fmaf(wrow[e * 3 + 1], x, a1);
    a2 = fmaf(wrow[e * 3 + 2], x, a2);
  }
  float sc = g1[h] * rsqrtf(vr1[h] + EPS_);
  G[((size_t)0 * V_ + v) * H_ + h] = a0 * sc;
  G[((size_t)1 * V_ + v) * H_ + h] = a1 * sc;
  G[((size_t)2 * V_ + v) * H_ + h] = a2 * sc;
}

// K1b: repack/split w2 -> A2 (H x 1536, j = k*C + c), fold scale2; biases.
// grid = H_ blocks, 256 threads
__global__ void a2_kernel(const float* __restrict__ w2,
                          const float* __restrict__ b1, const float* __restrict__ g1,
                          const float* __restrict__ be1, const float* __restrict__ mn1,
                          const float* __restrict__ vr1,
                          const float* __restrict__ b2, const float* __restrict__ g2,
                          const float* __restrict__ be2, const float* __restrict__ mn2,
                          const float* __restrict__ vr2,
                          float* __restrict__ bias1, float* __restrict__ bias2,
                          unsigned short* __restrict__ A2h, unsigned short* __restrict__ A2l) {
  int h = blockIdx.x;
  int tid = threadIdx.x;
  float sc1 = g1[h] * rsqrtf(vr1[h] + EPS_);
  float sc2 = g2[h] * rsqrtf(vr2[h] + EPS_);
  if (tid == 0) {
    bias1[h] = b1[h] * sc1 + be1[h] - mn1[h] * sc1;
    bias2[h] = b2[h] * sc2 + be2[h] - mn2[h] * sc2;
  }
  for (int j = tid; j < 3 * C_; j += 256) {
    int k = j >> 9;        // j / 512
    int c = j & (C_ - 1);  // j % 512
    float val = w2[((size_t)h * C_ + c) * 3 + k] * sc2;
    unsigned short hi = f2bf(val);
    A2h[(size_t)h * (3 * C_) + j] = hi;
    A2l[(size_t)h * (3 * C_) + j] = f2bf(val - bf2f(hi));
  }
}

// K2: h1T[b][r][c] (padded rows r in [0,P+2); r=0 and r=P+1 are zeros)
// h1 = relu(G0[id(p-1)] + G1[id(p)] + G2[id(p+1)] + bias1), split to bf16 hi/lo
// grid = B_*(P_+2) blocks, 256 threads
__global__ void embed_conv1_kernel(const int* __restrict__ ids, const float* __restrict__ G,
                                   const float* __restrict__ bias1,
                                   unsigned short* __restrict__ Bh, unsigned short* __restrict__ Bl) {
  int r = blockIdx.x % (P_ + 2);
  int b = blockIdx.x / (P_ + 2);
  int tid = threadIdx.x;
  size_t outbase = ((size_t)b * (P_ + 2) + r) * C_;
  if (r == 0 || r == P_ + 1) {
    for (int c = tid; c < C_; c += 256) { Bh[outbase + c] = 0; Bl[outbase + c] = 0; }
    return;
  }
  int p = r - 1;
  int v0 = (p >= 1) ? ids[b * P_ + p - 1] : -1;
  int v1 = ids[b * P_ + p];
  int v2 = (p + 1 < P_) ? ids[b * P_ + p + 1] : -1;
  const float* G0 = (v0 >= 0) ? (G + ((size_t)0 * V_ + v0) * H_) : nullptr;
  const float* G1 = G + ((size_t)1 * V_ + v1) * H_;
  const float* G2 = (v2 >= 0) ? (G + ((size_t)2 * V_ + v2) * H_) : nullptr;
  for (int c = tid; c < C_; c += 256) {
    float s = bias1[c] + G1[c];
    if (G0) s += G0[c];
    if (G2) s += G2[c];
    s = fmaxf(s, 0.f);
    unsigned short hi = f2bf(s);
    Bh[outbase + c] = hi;
    Bl[outbase + c] = f2bf(s - bf2f(hi));
  }
}

// K4: per-batch inclusive cumsum of durations. grid = B_, 1024 threads
__global__ void cumsum_kernel(const int* __restrict__ dur, int* __restrict__ cum) {
  __shared__ int s[P_];
  int b = blockIdx.x;
  int t = threadIdx.x;
  s[t] = dur[b * P_ + t];
  __syncthreads();
  for (int off = 1; off < P_; off <<= 1) {
    int v = (t >= off) ? s[t - off] : 0;
    __syncthreads();
    s[t] += v;
    __syncthreads();
  }
  cum[b * P_ + t] = s[t];
}

// K3: conv2 GEMM. M=512 (h), N=B*P (cols), K=1536. Split-bf16, 3 MFMA products.
// out2[b][h][p] = relu(acc + bias2[h]).  128x128 tile, BK=32, 256 threads (4 waves).
#define BM 128
#define BN 128
#define BK 32
__global__ __launch_bounds__(256) void conv2_gemm_kernel(
    const unsigned short* __restrict__ A2h, const unsigned short* __restrict__ A2l,
    const unsigned short* __restrict__ Bh, const unsigned short* __restrict__ Bl,
    const float* __restrict__ bias2, float* __restrict__ out2) {
  __shared__ __align__(16) unsigned short lds[4][BM * BK];  // Ah, Al, Bh, Bl tiles

  int tid = threadIdx.x;
  int w = tid >> 6;
  int l = tid & 63;
  int m0 = blockIdx.y * BM;
  int n0 = blockIdx.x * BN;
  int b = n0 >> 10;       // P_ = 1024
  int p0 = n0 & (P_ - 1);

  const unsigned short* Ah_base = A2h + (size_t)m0 * (3 * C_);
  const unsigned short* Al_base = A2l + (size_t)m0 * (3 * C_);
  const unsigned short* Bh_base = Bh + ((size_t)b * (P_ + 2) + p0) * C_;
  const unsigned short* Bl_base = Bl + ((size_t)b * (P_ + 2) + p0) * C_;

  f32x4 acc[4][4] = {};

  int srow = l >> 2;        // + seg*16
  int scol = (l & 3) * 8;   // element col within BK
  int fr = l & 15, fq = l >> 4;
  int wr = (w >> 1) * 64, wc = (w & 1) * 64;

  for (int kt = 0; kt < (3 * C_) / BK; ++kt) {
    int kofs = kt * BK;
#pragma unroll
    for (int q = 0; q < 2; ++q) {
      int seg = q * 4 + w;               // 0..7, wave-uniform
      int row = seg * 16 + srow;         // 0..127
      int col = kofs + scol;
      // HW writes lane l at ldsbase + l*16 bytes; source addr is per-lane.
      __builtin_amdgcn_global_load_lds(GLB(Ah_base + (size_t)row * (3 * C_) + col),
                                       LDSP(&lds[0][seg * 512]), 16, 0, 0);
      __builtin_amdgcn_global_load_lds(GLB(Al_base + (size_t)row * (3 * C_) + col),
                                       LDSP(&lds[1][seg * 512]), 16, 0, 0);
      __builtin_amdgcn_global_load_lds(GLB(Bh_base + (size_t)row * C_ + col),
                                       LDSP(&lds[2][seg * 512]), 16, 0, 0);
      __builtin_amdgcn_global_load_lds(GLB(Bl_base + (size_t)row * C_ + col),
                                       LDSP(&lds[3][seg * 512]), 16, 0, 0);
    }
    __syncthreads();

    bf16x8 ah[4], al[4], bh[4], bl[4];
#pragma unroll
    for (int i = 0; i < 4; ++i) {
      ah[i] = *(const bf16x8*)&lds[0][(wr + i * 16 + fr) * BK + fq * 8];
      al[i] = *(const bf16x8*)&lds[1][(wr + i * 16 + fr) * BK + fq * 8];
    }
#pragma unroll
    for (int j = 0; j < 4; ++j) {
      bh[j] = *(const bf16x8*)&lds[2][(wc + j * 16 + fr) * BK + fq * 8];
      bl[j] = *(const bf16x8*)&lds[3][(wc + j * 16 + fr) * BK + fq * 8];
    }
#pragma unroll
    for (int i = 0; i < 4; ++i)
#pragma unroll
      for (int j = 0; j < 4; ++j) {
        acc[i][j] = __builtin_amdgcn_mfma_f32_16x16x32_bf16(ah[i], bh[j], acc[i][j], 0, 0, 0);
        acc[i][j] = __builtin_amdgcn_mfma_f32_16x16x32_bf16(ah[i], bl[j], acc[i][j], 0, 0, 0);
        acc[i][j] = __builtin_amdgcn_mfma_f32_16x16x32_bf16(al[i], bh[j], acc[i][j], 0, 0, 0);
      }
    __syncthreads();
  }

  // Epilogue: C/D layout col = lane&15 (n), row = (lane>>4)*4 + reg (m)
#pragma unroll
  for (int i = 0; i < 4; ++i) {
#pragma unroll
    for (int j = 0; j < 4; ++j) {
#pragma unroll
      for (int r = 0; r < 4; ++r) {
        int m = m0 + wr + i * 16 + fq * 4 + r;  // h
        int n = n0 + wc + j * 16 + fr;          // global col
        int bb = n >> 10;
        int p = n & (P_ - 1);
        float v = acc[i][j][r] + bias2[m];
        v = fmaxf(v, 0.f);
        out2[((size_t)bb * H_ + m) * P_ + p] = v;
      }
    }
  }
}

// K5: upsample. grid = (ceil(T/256), B_), 256 threads.
__global__ void upsample_kernel(const float* __restrict__ out2, const int* __restrict__ cum,
                                float* __restrict__ out, int T) {
  __shared__ int sc[P_];
  int b = blockIdx.y;
  int tid = threadIdx.x;
  for (int i = tid; i < P_; i += 256) sc[i] = cum[b * P_ + i];
  __syncthreads();
  int t = blockIdx.x * 256 + tid;
  if (t >= T) return;
  int tot = sc[P_ - 1];
  bool valid = (t < tot);
  int idx = 0;
  if (valid) {
    int lo = 0, hi = P_;
    while (lo < hi) {
      int mid = (lo + hi) >> 1;
      if (sc[mid] <= t) lo = mid + 1; else hi = mid;
    }
    idx = min(lo, P_ - 1);
  }
  const float* src = out2 + (size_t)b * H_ * P_ + idx;
  float* dst = out + (size_t)b * H_ * T + t;
  if (valid) {
    for (int h = 0; h < H_; ++h) dst[(size_t)h * T] = src[(size_t)h * P_];
  } else {
    for (int h = 0; h < H_; ++h) dst[(size_t)h * T] = 0.f;
  }
}

static inline size_t align256(size_t x) { return (x + 255) & ~(size_t)255; }

extern "C" void kernel_launch(void* const* d_in, const int* in_sizes, int n_in,
                              void* d_out, int out_size, void* d_ws, size_t ws_size,
                              hipStream_t stream) {
  const int*   ids = (const int*)d_in[0];
  const int*   dur = (const int*)d_in[1];
  const float* emb = (const float*)d_in[2];
  const float* w1  = (const float*)d_in[3];
  const float* b1  = (const float*)d_in[4];
  const float* g1  = (const float*)d_in[5];
  const float* be1 = (const float*)d_in[6];
  const float* mn1 = (const float*)d_in[7];
  const float* vr1 = (const float*)d_in[8];
  const float* w2  = (const float*)d_in[9];
  const float* b2  = (const float*)d_in[10];
  const float* g2  = (const float*)d_in[11];
  const float* be2 = (const float*)d_in[12];
  const float* mn2 = (const float*)d_in[13];
  const float* vr2 = (const float*)d_in[14];
  float* out = (float*)d_out;

  int T = out_size / (B_ * H_);

  char* ws = (char*)d_ws;
  size_t off = 0;
  auto carve = [&](size_t bytes) { void* p = ws + off; off = align256(off + bytes); return p; };
  float* G              = (float*)carve((size_t)3 * V_ * H_ * 4);
  float* bias1          = (float*)carve(H_ * 4);
  float* bias2          = (float*)carve(H_ * 4);
  unsigned short* A2h   = (unsigned short*)carve((size_t)H_ * 3 * C_ * 2);
  unsigned short* A2l   = (unsigned short*)carve((size_t)H_ * 3 * C_ * 2);
  unsigned short* Bhv   = (unsigned short*)carve((size_t)B_ * (P_ + 2) * C_ * 2);
  unsigned short* Blv   = (unsigned short*)carve((size_t)B_ * (P_ + 2) * C_ * 2);
  float* out2           = (float*)carve((size_t)B_ * H_ * P_ * 4);
  int* cum              = (int*)carve((size_t)B_ * P_ * 4);

  g_kernel<<<V_, E_, 0, stream>>>(emb, w1, g1, vr1, G);
  a2_kernel<<<H_, 256, 0, stream>>>(w2, b1, g1, be1, mn1, vr1, b2, g2, be2, mn2, vr2,
                                    bias1, bias2, A2h, A2l);
  embed_conv1_kernel<<<B_ * (P_ + 2), 256, 0, stream>>>(ids, G, bias1, Bhv, Blv);
  cumsum_kernel<<<B_, P_, 0, stream>>>(dur, cum);
  conv2_gemm_kernel<<<dim3((B_ * P_) / BN, H_ / BM), 256, 0, stream>>>(A2h, A2l, Bhv, Blv,
                                                                       bias2, out2);
  upsample_kernel<<<dim3((T + 255) / 256, B_), 256, 0, stream>>>(out2, cum, out, T);
}

// Round 2
// 698.329 us; speedup vs baseline: 1.0659x; 1.0659x over previous
//
#include <hip/hip_runtime.h>

#define B_ 32
#define P_ 1024
#define V_ 100
#define E_ 512
#define H_ 512
#define C_ 512
#define EPS_ 1e-5f

typedef float f32x4 __attribute__((ext_vector_type(4)));
typedef short bf16x8 __attribute__((ext_vector_type(8)));

#define GLB(p) ((const __attribute__((address_space(1))) unsigned int*)(p))
#define LDSP(p) ((__attribute__((address_space(3))) unsigned int*)(p))

__device__ __forceinline__ unsigned short f2bf(float f) {
  unsigned int u = __float_as_uint(f);
  u += 0x7fffu + ((u >> 16) & 1u);
  return (unsigned short)(u >> 16);
}
__device__ __forceinline__ float bf2f(unsigned short s) {
  return __uint_as_float(((unsigned int)s) << 16);
}

// K0: transpose w1 [H][E*3] -> w1T [E*3][H]  (one-time, 3 MB)
// grid (H/64, 1536/64), 256 threads
__global__ __launch_bounds__(256) void w1t_kernel(const float* __restrict__ w1,
                                                  float* __restrict__ w1T) {
  __shared__ float tile[64][65];
  int h0 = blockIdx.x * 64;
  int e0 = blockIdx.y * 64;  // ek = e*3+k flat index
  int t = threadIdx.x;
  int c = t & 63, r4 = t >> 6;
#pragma unroll
  for (int r = 0; r < 64; r += 4)
    tile[r + r4][c] = w1[(size_t)(h0 + r + r4) * 1536 + e0 + c];
  __syncthreads();
#pragma unroll
  for (int r = 0; r < 64; r += 4)
    w1T[(size_t)(e0 + r + r4) * 512 + h0 + c] = tile[c][r + r4];
}

// K1: G[k][v][h] = scale1[h] * sum_e w1T[3e+k][h] * emb[v,e]
// grid (V_, H_/64), 64 threads. All loads coalesced; w1T slice L2-resident.
__global__ __launch_bounds__(64) void g_kernel(const float* __restrict__ emb,
                                               const float* __restrict__ w1T,
                                               const float* __restrict__ g1,
                                               const float* __restrict__ vr1,
                                               float* __restrict__ G) {
  __shared__ float se[E_];
  int v = blockIdx.x;
  int h = blockIdx.y * 64 + threadIdx.x;
  for (int i = threadIdx.x; i < E_; i += 64) se[i] = emb[(size_t)v * E_ + i];
  __syncthreads();
  float a0 = 0.f, a1 = 0.f, a2 = 0.f;
#pragma unroll 4
  for (int e = 0; e < E_; ++e) {
    float x = se[e];
    const float* wp = w1T + (size_t)(3 * e) * H_ + h;
    a0 = fmaf(wp[0], x, a0);
    a1 = fmaf(wp[H_], x, a1);
    a2 = fmaf(wp[2 * H_], x, a2);
  }
  float sc = g1[h] * rsqrtf(vr1[h] + EPS_);
  G[((size_t)0 * V_ + v) * H_ + h] = a0 * sc;
  G[((size_t)1 * V_ + v) * H_ + h] = a1 * sc;
  G[((size_t)2 * V_ + v) * H_ + h] = a2 * sc;
}

// K1b: repack/split w2 -> A2 (H x 1536, j = k*C + c), fold scale2; biases.
__global__ __launch_bounds__(256) void a2_kernel(
    const float* __restrict__ w2, const float* __restrict__ b1,
    const float* __restrict__ g1, const float* __restrict__ be1,
    const float* __restrict__ mn1, const float* __restrict__ vr1,
    const float* __restrict__ b2, const float* __restrict__ g2,
    const float* __restrict__ be2, const float* __restrict__ mn2,
    const float* __restrict__ vr2, float* __restrict__ bias1,
    float* __restrict__ bias2, unsigned short* __restrict__ A2h,
    unsigned short* __restrict__ A2l) {
  int h = blockIdx.x;
  int tid = threadIdx.x;
  float sc1 = g1[h] * rsqrtf(vr1[h] + EPS_);
  float sc2 = g2[h] * rsqrtf(vr2[h] + EPS_);
  if (tid == 0) {
    bias1[h] = b1[h] * sc1 + be1[h] - mn1[h] * sc1;
    bias2[h] = b2[h] * sc2 + be2[h] - mn2[h] * sc2;
  }
  for (int j = tid; j < 3 * C_; j += 256) {
    int k = j >> 9;
    int c = j & (C_ - 1);
    float val = w2[((size_t)h * C_ + c) * 3 + k] * sc2;
    unsigned short hi = f2bf(val);
    A2h[(size_t)h * (3 * C_) + j] = hi;
    A2l[(size_t)h * (3 * C_) + j] = f2bf(val - bf2f(hi));
  }
}

// K2: h1T[b][r][c] padded rows (r=0, r=P+1 zero); 2 channels/thread, packed stores
// grid = B_*(P_+2), 256 threads
__global__ __launch_bounds__(256) void embed_conv1_kernel(
    const int* __restrict__ ids, const float* __restrict__ G,
    const float* __restrict__ bias1, unsigned short* __restrict__ Bh,
    unsigned short* __restrict__ Bl) {
  int r = blockIdx.x % (P_ + 2);
  int b = blockIdx.x / (P_ + 2);
  int t = threadIdx.x;
  size_t outbase = ((size_t)b * (P_ + 2) + r) * C_;
  unsigned int* BhU = (unsigned int*)(Bh + outbase);
  unsigned int* BlU = (unsigned int*)(Bl + outbase);
  if (r == 0 || r == P_ + 1) {
    BhU[t] = 0u;
    BlU[t] = 0u;
    return;
  }
  int p = r - 1;
  int v0 = (p >= 1) ? ids[b * P_ + p - 1] : -1;
  int v1 = ids[b * P_ + p];
  int v2 = (p + 1 < P_) ? ids[b * P_ + p + 1] : -1;
  const float2* G0 = (v0 >= 0) ? (const float2*)(G + ((size_t)0 * V_ + v0) * H_) : nullptr;
  const float2* G1 = (const float2*)(G + ((size_t)1 * V_ + v1) * H_);
  const float2* G2 = (v2 >= 0) ? (const float2*)(G + ((size_t)2 * V_ + v2) * H_) : nullptr;
  const float2* bi = (const float2*)bias1;

  float2 s = bi[t];
  float2 gm = G1[t];
  s.x += gm.x;
  s.y += gm.y;
  if (G0) {
    float2 g0 = G0[t];
    s.x += g0.x;
    s.y += g0.y;
  }
  if (G2) {
    float2 g2v = G2[t];
    s.x += g2v.x;
    s.y += g2v.y;
  }
  s.x = fmaxf(s.x, 0.f);
  s.y = fmaxf(s.y, 0.f);
  unsigned short h0 = f2bf(s.x), h1 = f2bf(s.y);
  unsigned short l0 = f2bf(s.x - bf2f(h0)), l1 = f2bf(s.y - bf2f(h1));
  BhU[t] = (unsigned int)h0 | ((unsigned int)h1 << 16);
  BlU[t] = (unsigned int)l0 | ((unsigned int)l1 << 16);
}

// K4: per-batch inclusive cumsum. grid = B_, 1024 threads
__global__ __launch_bounds__(1024) void cumsum_kernel(const int* __restrict__ dur,
                                                      int* __restrict__ cum) {
  __shared__ int s[P_];
  int b = blockIdx.x;
  int t = threadIdx.x;
  s[t] = dur[b * P_ + t];
  __syncthreads();
  for (int off = 1; off < P_; off <<= 1) {
    int v = (t >= off) ? s[t - off] : 0;
    __syncthreads();
    s[t] += v;
    __syncthreads();
  }
  cum[b * P_ + t] = s[t];
}

// K3: conv2 GEMM. M=512 (h), N=B*P, K=1536. Split-bf16, 3 MFMA products.
// 128x128 tile, BK=32, 4 waves. 1D grid, m-major + XCD-chunk swizzle.
#define BM 128
#define BN 128
#define BK 32
__global__ __launch_bounds__(256) void conv2_gemm_kernel(
    const unsigned short* __restrict__ A2h, const unsigned short* __restrict__ A2l,
    const unsigned short* __restrict__ Bh, const unsigned short* __restrict__ Bl,
    const float* __restrict__ bias2, float* __restrict__ out2) {
  __shared__ __align__(16) unsigned short lds[4][BM * BK];  // Ah, Al, Bh, Bl

  int tid = threadIdx.x;
  int w = tid >> 6;
  int l = tid & 63;

  // XCD-aware swizzle: 1024 blocks, 8 XCDs, chunk 128. m-major within chunk
  // so each XCD keeps one 786KB A-slice L2-resident; B panels L3-shared.
  int bid = blockIdx.x;
  int wg = ((bid & 7) << 7) | (bid >> 3);
  int m0 = (wg >> 8) * BM;   // 0..3 * 128
  int n0 = (wg & 255) * BN;  // 0..255 * 128
  int b = n0 >> 10;
  int p0 = n0 & (P_ - 1);

  const unsigned short* Ah_base = A2h + (size_t)m0 * (3 * C_);
  const unsigned short* Al_base = A2l + (size_t)m0 * (3 * C_);
  const unsigned short* Bh_base = Bh + ((size_t)b * (P_ + 2) + p0) * C_;
  const unsigned short* Bl_base = Bl + ((size_t)b * (P_ + 2) + p0) * C_;

  f32x4 acc[4][4] = {};

  int srow = l >> 2;
  int scol = (l & 3) * 8;
  int fr = l & 15, fq = l >> 4;
  int wr = (w >> 1) * 64, wc = (w & 1) * 64;

  for (int kt = 0; kt < (3 * C_) / BK; ++kt) {
    int kofs = kt * BK;
#pragma unroll
    for (int q = 0; q < 2; ++q) {
      int seg = q * 4 + w;
      int row = seg * 16 + srow;
      int col = kofs + scol;
      __builtin_amdgcn_global_load_lds(GLB(Ah_base + (size_t)row * (3 * C_) + col),
                                       LDSP(&lds[0][seg * 512]), 16, 0, 0);
      __builtin_amdgcn_global_load_lds(GLB(Al_base + (size_t)row * (3 * C_) + col),
                                       LDSP(&lds[1][seg * 512]), 16, 0, 0);
      __builtin_amdgcn_global_load_lds(GLB(Bh_base + (size_t)row * C_ + col),
                                       LDSP(&lds[2][seg * 512]), 16, 0, 0);
      __builtin_amdgcn_global_load_lds(GLB(Bl_base + (size_t)row * C_ + col),
                                       LDSP(&lds[3][seg * 512]), 16, 0, 0);
    }
    __syncthreads();

    bf16x8 ah[4], al[4], bh[4], bl[4];
#pragma unroll
    for (int i = 0; i < 4; ++i) {
      ah[i] = *(const bf16x8*)&lds[0][(wr + i * 16 + fr) * BK + fq * 8];
      al[i] = *(const bf16x8*)&lds[1][(wr + i * 16 + fr) * BK + fq * 8];
    }
#pragma unroll
    for (int j = 0; j < 4; ++j) {
      bh[j] = *(const bf16x8*)&lds[2][(wc + j * 16 + fr) * BK + fq * 8];
      bl[j] = *(const bf16x8*)&lds[3][(wc + j * 16 + fr) * BK + fq * 8];
    }
#pragma unroll
    for (int i = 0; i < 4; ++i)
#pragma unroll
      for (int j = 0; j < 4; ++j) {
        acc[i][j] = __builtin_amdgcn_mfma_f32_16x16x32_bf16(ah[i], bh[j], acc[i][j], 0, 0, 0);
        acc[i][j] = __builtin_amdgcn_mfma_f32_16x16x32_bf16(ah[i], bl[j], acc[i][j], 0, 0, 0);
        acc[i][j] = __builtin_amdgcn_mfma_f32_16x16x32_bf16(al[i], bh[j], acc[i][j], 0, 0, 0);
      }
    __syncthreads();
  }

  // C/D layout: col = lane&15 (n), row = (lane>>4)*4 + reg (m)
#pragma unroll
  for (int i = 0; i < 4; ++i) {
#pragma unroll
    for (int j = 0; j < 4; ++j) {
#pragma unroll
      for (int r = 0; r < 4; ++r) {
        int m = m0 + wr + i * 16 + fq * 4 + r;
        int n = n0 + wc + j * 16 + fr;
        int bb = n >> 10;
        int p = n & (P_ - 1);
        float v = acc[i][j][r] + bias2[m];
        v = fmaxf(v, 0.f);
        out2[((size_t)bb * H_ + m) * P_ + p] = v;
      }
    }
  }
}

// K5: upsample. grid = (ceil(T/256), B_), 256 threads.
__global__ __launch_bounds__(256) void upsample_kernel(const float* __restrict__ out2,
                                                       const int* __restrict__ cum,
                                                       float* __restrict__ out, int T) {
  __shared__ int sc[P_];
  int b = blockIdx.y;
  int tid = threadIdx.x;
  for (int i = tid; i < P_; i += 256) sc[i] = cum[b * P_ + i];
  __syncthreads();
  int t = blockIdx.x * 256 + tid;
  if (t >= T) return;
  int tot = sc[P_ - 1];
  bool valid = (t < tot);
  int idx = 0;
  if (valid) {
    int lo = 0, hi = P_;
    while (lo < hi) {
      int mid = (lo + hi) >> 1;
      if (sc[mid] <= t) lo = mid + 1; else hi = mid;
    }
    idx = min(lo, P_ - 1);
  }
  const float* src = out2 + (size_t)b * H_ * P_ + idx;
  float* dst = out + (size_t)b * H_ * T + t;
  if (valid) {
    for (int h = 0; h < H_; ++h) dst[(size_t)h * T] = src[(size_t)h * P_];
  } else {
    for (int h = 0; h < H_; ++h) dst[(size_t)h * T] = 0.f;
  }
}

static inline size_t align256(size_t x) { return (x + 255) & ~(size_t)255; }

extern "C" void kernel_launch(void* const* d_in, const int* in_sizes, int n_in,
                              void* d_out, int out_size, void* d_ws, size_t ws_size,
                              hipStream_t stream) {
  const int*   ids = (const int*)d_in[0];
  const int*   dur = (const int*)d_in[1];
  const float* emb = (const float*)d_in[2];
  const float* w1  = (const float*)d_in[3];
  const float* b1  = (const float*)d_in[4];
  const float* g1  = (const float*)d_in[5];
  const float* be1 = (const float*)d_in[6];
  const float* mn1 = (const float*)d_in[7];
  const float* vr1 = (const float*)d_in[8];
  const float* w2  = (const float*)d_in[9];
  const float* b2  = (const float*)d_in[10];
  const float* g2  = (const float*)d_in[11];
  const float* be2 = (const float*)d_in[12];
  const float* mn2 = (const float*)d_in[13];
  const float* vr2 = (const float*)d_in[14];
  float* out = (float*)d_out;

  int T = out_size / (B_ * H_);

  char* ws = (char*)d_ws;
  size_t off = 0;
  auto carve = [&](size_t bytes) { void* p = ws + off; off = align256(off + bytes); return p; };
  float* G              = (float*)carve((size_t)3 * V_ * H_ * 4);
  float* w1T            = (float*)carve((size_t)3 * E_ * H_ * 4);
  float* bias1          = (float*)carve(H_ * 4);
  float* bias2          = (float*)carve(H_ * 4);
  unsigned short* A2h   = (unsigned short*)carve((size_t)H_ * 3 * C_ * 2);
  unsigned short* A2l   = (unsigned short*)carve((size_t)H_ * 3 * C_ * 2);
  unsigned short* Bhv   = (unsigned short*)carve((size_t)B_ * (P_ + 2) * C_ * 2);
  unsigned short* Blv   = (unsigned short*)carve((size_t)B_ * (P_ + 2) * C_ * 2);
  float* out2           = (float*)carve((size_t)B_ * H_ * P_ * 4);
  int* cum              = (int*)carve((size_t)B_ * P_ * 4);

  w1t_kernel<<<dim3(H_ / 64, (3 * E_) / 64), 256, 0, stream>>>(w1, w1T);
  a2_kernel<<<H_, 256, 0, stream>>>(w2, b1, g1, be1, mn1, vr1, b2, g2, be2, mn2, vr2,
                                    bias1, bias2, A2h, A2l);
  g_kernel<<<dim3(V_, H_ / 64), 64, 0, stream>>>(emb, w1T, g1, vr1, G);
  embed_conv1_kernel<<<B_ * (P_ + 2), 256, 0, stream>>>(ids, G, bias1, Bhv, Blv);
  cumsum_kernel<<<B_, P_, 0, stream>>>(dur, cum);
  conv2_gemm_kernel<<<(B_ * P_ / BN) * (H_ / BM), 256, 0, stream>>>(A2h, A2l, Bhv, Blv,
                                                                    bias2, out2);
  upsample_kernel<<<dim3((T + 255) / 256, B_), 256, 0, stream>>>(out2, cum, out, T);
}